// Round 2
// baseline (579.421 us; speedup 1.0000x reference)
//
#include <hip/hip_runtime.h>
#include <hip/hip_bf16.h>
#include <math.h>

typedef __bf16 bf16_t;
typedef _Float16 f16_t;
typedef bf16_t bf16x8 __attribute__((ext_vector_type(8)));
typedef bf16_t bf16x4 __attribute__((ext_vector_type(4)));
typedef f16_t  f16x8  __attribute__((ext_vector_type(8)));
typedef f16_t  f16x4  __attribute__((ext_vector_type(4)));
typedef float  f32x4  __attribute__((ext_vector_type(4)));

// ---------------------------------------------------------------------------
// fp32 -> bf16 conversion, float4 loads, 8B stores
// ---------------------------------------------------------------------------
__global__ __launch_bounds__(256) void cvt_f32_bf16(
    const float* __restrict__ in, bf16_t* __restrict__ out, int n4) {
  int i = blockIdx.x * 256 + threadIdx.x;
  if (i >= n4) return;
  float4 v = ((const float4*)in)[i];
  bf16x4 o;
  o[0] = (bf16_t)v.x; o[1] = (bf16_t)v.y; o[2] = (bf16_t)v.z; o[3] = (bf16_t)v.w;
  ((bf16x4*)out)[i] = o;
}

// ---------------------------------------------------------------------------
// bf16 LDS-tiled transpose: in [R,C] -> out [C,R], per-batch via blockIdx.z
// ---------------------------------------------------------------------------
__global__ __launch_bounds__(256) void transpose_bf16(
    const bf16_t* __restrict__ in, bf16_t* __restrict__ out, int R, int C) {
  __shared__ bf16_t t[64][65];
  size_t boff = (size_t)blockIdx.z * R * C;
  in += boff; out += boff;
  int r0 = blockIdx.y * 64, c0 = blockIdx.x * 64;
  int x = threadIdx.x & 63, y4 = threadIdx.x >> 6;
  #pragma unroll
  for (int yy = y4; yy < 64; yy += 4)
    t[yy][x] = in[(size_t)(r0 + yy) * C + c0 + x];
  __syncthreads();
  #pragma unroll
  for (int yy = y4; yy < 64; yy += 4)
    out[(size_t)(c0 + yy) * R + r0 + x] = t[x][yy];
}

// ---------------------------------------------------------------------------
// Row softmax over fp16 logits [nrows x 2048]; overwrites each row in place
// with normalized bf16 P (same 2-byte element pitch, same row addresses).
// ---------------------------------------------------------------------------
__global__ __launch_bounds__(256) void softmax_rows_f16(f16_t* __restrict__ sc) {
  f16_t* rp = sc + (size_t)blockIdx.x * 2048;
  int tid = threadIdx.x;
  f16x8 v = ((const f16x8*)rp)[tid];
  float f[8];
  #pragma unroll
  for (int t = 0; t < 8; t++) f[t] = (float)v[t];

  float m = f[0];
  #pragma unroll
  for (int t = 1; t < 8; t++) m = fmaxf(m, f[t]);
  #pragma unroll
  for (int o = 32; o; o >>= 1) m = fmaxf(m, __shfl_xor(m, o));
  __shared__ float redm[4];
  if ((tid & 63) == 0) redm[tid >> 6] = m;
  __syncthreads();
  m = fmaxf(fmaxf(redm[0], redm[1]), fmaxf(redm[2], redm[3]));

  float s = 0.f;
  #pragma unroll
  for (int t = 0; t < 8; t++) { f[t] = __expf(f[t] - m); s += f[t]; }
  #pragma unroll
  for (int o = 32; o; o >>= 1) s += __shfl_xor(s, o);
  __shared__ float reds[4];
  if ((tid & 63) == 0) reds[tid >> 6] = s;
  __syncthreads();
  s = reds[0] + reds[1] + reds[2] + reds[3];
  float inv = 1.0f / s;

  bf16x8 o8;
  #pragma unroll
  for (int t = 0; t < 8; t++) o8[t] = (bf16_t)(f[t] * inv);
  ((bf16x8*)rp)[tid] = o8;
}

// ---------------------------------------------------------------------------
// epilogue store helpers (full-line coalesced vector stores)
// ---------------------------------------------------------------------------
__device__ __forceinline__ void store4(float* p, float4 v) { *(float4*)p = v; }
__device__ __forceinline__ void store4(bf16_t* p, float4 v) {
  bf16x4 o; o[0] = (bf16_t)v.x; o[1] = (bf16_t)v.y;
  o[2] = (bf16_t)v.z; o[3] = (bf16_t)v.w; *(bf16x4*)p = o;
}
__device__ __forceinline__ void store4(f16_t* p, float4 v) {
  f16x4 o; o[0] = (f16_t)v.x; o[1] = (f16_t)v.y;
  o[2] = (f16_t)v.z; o[3] = (f16_t)v.w; *(f16x4*)p = o;
}

// ---------------------------------------------------------------------------
// 256x256 8-phase bf16 MFMA GEMM, C = scale * (A @ B^T) + bias.
//   A [M,K] row-major (lda), B [N,K] row-major (ldb), C [M,N] (ldc).
//   512 threads = 8 waves (2 Mwave x 4 Nwave), per-wave C = 128x64.
// LDS: 10-slot ring of 16KB half-slots (160 KiB, full CU LDS). Logical half
// h (tile h>>2; kind h&3: 0=A0,1=A1,2=B0,3=B1) lives in slot h%10. During
// tile t the four phases stage tile t+2's halves (4t+8..4t+11) -- a FULL
// K-tile of prefetch lead -- and the tile-boundary s_waitcnt vmcnt(8) waits
// only on loads issued one full tile earlier (tile t+1's halves, staged
// during tile t-1). Overwrite safety (all verified against the two barriers
// per phase): 4t+8 -> slot of (t-1).B0 (last read t-1 ph3); 4t+9 -> (t-1).B1;
// 4t+10 -> t.A0 (last read ph2, staged ph3); 4t+11 -> t.A1 (ph4).
// st_16x32 LDS swizzle (T2) via inverse-swizzled GLOBAL source (linear
// global_load_lds dest) + swizzled ds_read. setprio around MFMA (T5).
// Requires M%256==0, N%256==0, K%192==0... (nk>=3), lda/ldb 8-elem aligned.
// batch_on_x=1: batch=blockIdx.x (≈XCD id) for L2 locality.
// ---------------------------------------------------------------------------
#define BM 256
#define BN 256
#define BK 64

__device__ __forceinline__ void load16_lds(const bf16_t* g, bf16_t* l) {
  __builtin_amdgcn_global_load_lds(
      (__attribute__((address_space(1))) void*)const_cast<bf16_t*>(g),
      (__attribute__((address_space(3))) void*)l, 16, 0, 0);
}

template <typename CT>
__global__ __launch_bounds__(512, 2) void gemm256(
    const bf16_t* __restrict__ A, int lda, size_t strA,
    const bf16_t* __restrict__ B, int ldb, size_t strB,
    CT* __restrict__ C, int ldc, size_t strC,
    const float* __restrict__ bias, float scale,
    int K, int batch_on_x) {
  __shared__ __align__(16) char smem[10][16384];  // 160 KiB ring
  char* smem0 = &smem[0][0];

  int bz, mt, nt;
  if (batch_on_x) { bz = blockIdx.x; nt = blockIdx.y; mt = blockIdx.z; }
  else            { mt = blockIdx.x; nt = blockIdx.y; bz = blockIdx.z; }
  A += (size_t)bz * strA;
  B += (size_t)bz * strB;
  C += (size_t)bz * strC;
  int m0 = mt * BM, n0 = nt * BN;
  int tid  = threadIdx.x;
  int lane = tid & 63, wv = tid >> 6;
  int wrow = wv >> 2;        // 0..1  (128 M-rows each)
  int wcol = wv & 3;         // 0..3  (64 N-cols each)

  f32x4 acc[8][4];
  #pragma unroll
  for (int i = 0; i < 8; i++)
    #pragma unroll
    for (int j = 0; j < 4; j++) acc[i][j] = (f32x4)0.f;

  int lrow = lane & 15;
  int lk8  = (lane >> 4) * 8;       // k element offset 0/8/16/24
  int xm   = (lrow & 8) << 2;       // st_16x32 read-side XOR (bit5)

  // swizzled ds_read of one bf16x8 fragment from a 16KB half-slot.
  // blk = local 16-row block (0..7) within the half; kcol = k element.
  auto rd = [&](const char* half, int blk, int kcol) -> bf16x8 {
    int byte = (((blk << 1) + (kcol >> 5)) << 10)
             + (lrow << 6) + (((kcol & 31) << 1) ^ xm);
    return *(const bf16x8*)(half + byte);
  };

  // stage logical half h into ring slot `slot`. LDS dest linear; global
  // source inverse-swizzled so swizzled ds_reads see (row, col) correctly.
  auto stage_half = [&](int h, int slot) {
    int th = h >> 2, hf = h & 3;
    char* dstb = smem0 + slot * 16384;
    const bf16_t* g; int rb, ld;
    if (hf < 2) { g = A; rb = m0 + hf * 128;       ld = lda; }
    else        { g = B; rb = n0 + (hf - 2) * 128; ld = ldb; }
    int k0 = th * BK;
    #pragma unroll
    for (int q = 0; q < 2; q++) {
      int l = q * 8192 + wv * 1024 + lane * 16;  // byte offset within half
      int inner = l & 1023, s = l >> 10;
      int rl   = ((s >> 1) << 4) | (inner >> 6);
      int colb = (inner & 63) ^ (((inner >> 9) & 1) << 5);
      int col  = ((s & 1) << 5) | (colb >> 1);
      load16_lds(g + (size_t)(rb + rl) * ld + k0 + col,
                 (bf16_t*)(dstb + q * 8192 + wv * 1024));
    }
  };

  int nk = K / BK;
  int nh = 4 * nk;

  // prologue: tiles 0 and 1 complete (halves 0..7 -> slots 0..7);
  // vmcnt(8) => tile 0 resident.
  #pragma unroll
  for (int h = 0; h < 8; ++h)
    if (h < nh) stage_half(h, h);
  asm volatile("s_waitcnt vmcnt(8)" ::: "memory");
  asm volatile("s_barrier" ::: "memory");

  bf16x8 a0[4][2], a1[4][2], bb[2][2];
  int rs = 0;    // ring slot of current tile's half 4t
  int ss = 8;    // next stage slot

  for (int t = 0; t < nk; ++t) {
    int hb = 4 * t + 8;                       // tile t+2's first half
    int sa = rs + wrow;                       // rs<=8 even, wrow<=1 -> <=9
    int sb = rs + 2 + (wcol >> 1); if (sb >= 10) sb -= 10;
    const char* Ah = smem0 + sa * 16384;      // this wave's A half
    const char* Bh = smem0 + sb * 16384;      // this wave's B half
    int bl = (wcol & 1) * 4;                  // B block base within half

    // ---- phase 1: read A rows 0-63 (8) + B cols 0-31 (4); stage (t+2).A0
    #pragma unroll
    for (int i = 0; i < 4; ++i)
      #pragma unroll
      for (int s = 0; s < 2; ++s)
        a0[i][s] = rd(Ah, i, s * 32 + lk8);
    #pragma unroll
    for (int j = 0; j < 2; ++j)
      #pragma unroll
      for (int s = 0; s < 2; ++s)
        bb[j][s] = rd(Bh, bl + j, s * 32 + lk8);
    if (hb + 0 < nh) { stage_half(hb + 0, ss); ss = (ss == 9) ? 0 : ss + 1; }
    asm volatile("s_barrier" ::: "memory");
    asm volatile("s_waitcnt lgkmcnt(0)");
    __builtin_amdgcn_s_setprio(1);
    #pragma unroll
    for (int i = 0; i < 4; ++i)
      #pragma unroll
      for (int j = 0; j < 2; ++j)
        #pragma unroll
        for (int s = 0; s < 2; ++s)
          acc[i][j] = __builtin_amdgcn_mfma_f32_16x16x32_bf16(
              a0[i][s], bb[j][s], acc[i][j], 0, 0, 0);
    __builtin_amdgcn_s_setprio(0);
    asm volatile("s_barrier" ::: "memory");

    // ---- phase 2: read A rows 64-127 (8); stage (t+2).A1; MFMA q10
    #pragma unroll
    for (int i = 0; i < 4; ++i)
      #pragma unroll
      for (int s = 0; s < 2; ++s)
        a1[i][s] = rd(Ah, 4 + i, s * 32 + lk8);
    if (hb + 1 < nh) { stage_half(hb + 1, ss); ss = (ss == 9) ? 0 : ss + 1; }
    asm volatile("s_barrier" ::: "memory");
    asm volatile("s_waitcnt lgkmcnt(0)");
    __builtin_amdgcn_s_setprio(1);
    #pragma unroll
    for (int i = 0; i < 4; ++i)
      #pragma unroll
      for (int j = 0; j < 2; ++j)
        #pragma unroll
        for (int s = 0; s < 2; ++s)
          acc[4 + i][j] = __builtin_amdgcn_mfma_f32_16x16x32_bf16(
              a1[i][s], bb[j][s], acc[4 + i][j], 0, 0, 0);
    __builtin_amdgcn_s_setprio(0);
    asm volatile("s_barrier" ::: "memory");

    // ---- phase 3: read B cols 32-63 (4); stage (t+2).B0; MFMA q11
    #pragma unroll
    for (int j = 0; j < 2; ++j)
      #pragma unroll
      for (int s = 0; s < 2; ++s)
        bb[j][s] = rd(Bh, bl + 2 + j, s * 32 + lk8);
    if (hb + 2 < nh) { stage_half(hb + 2, ss); ss = (ss == 9) ? 0 : ss + 1; }
    asm volatile("s_barrier" ::: "memory");
    asm volatile("s_waitcnt lgkmcnt(0)");
    __builtin_amdgcn_s_setprio(1);
    #pragma unroll
    for (int i = 0; i < 4; ++i)
      #pragma unroll
      for (int j = 0; j < 2; ++j)
        #pragma unroll
        for (int s = 0; s < 2; ++s)
          acc[4 + i][2 + j] = __builtin_amdgcn_mfma_f32_16x16x32_bf16(
              a1[i][s], bb[j][s], acc[4 + i][2 + j], 0, 0, 0);
    __builtin_amdgcn_s_setprio(0);
    asm volatile("s_barrier" ::: "memory");

    // ---- phase 4: stage (t+2).B1; MFMA q01; tile-boundary counted vmcnt
    if (hb + 3 < nh) { stage_half(hb + 3, ss); ss = (ss == 9) ? 0 : ss + 1; }
    asm volatile("s_barrier" ::: "memory");
    __builtin_amdgcn_s_setprio(1);
    #pragma unroll
    for (int i = 0; i < 4; ++i)
      #pragma unroll
      for (int j = 0; j < 2; ++j)
        #pragma unroll
        for (int s = 0; s < 2; ++s)
          acc[i][2 + j] = __builtin_amdgcn_mfma_f32_16x16x32_bf16(
              a0[i][s], bb[j][s], acc[i][2 + j], 0, 0, 0);
    __builtin_amdgcn_s_setprio(0);
    if (t < nk - 2) asm volatile("s_waitcnt vmcnt(8)" ::: "memory");
    else            asm volatile("s_waitcnt vmcnt(0)" ::: "memory");
    asm volatile("s_barrier" ::: "memory");

    rs += 4; if (rs >= 10) rs -= 10;
  }

  // ---- epilogue: repack C through LDS in 4 quarters of 64x256 fp32 ----
  // acc mapping [m89]: col = wcol*64 + j*16 + (lane&15),
  //                    row = wrow*128 + i*16 + (lane>>4)*4 + r
  float* Cs = (float*)smem0;         // 64 x 260 fp32 (~66 KB, fits ring)
  #pragma unroll
  for (int q = 0; q < 4; ++q) {
    __syncthreads();
    if (wrow == (q >> 1)) {          // wave-uniform branch
      #pragma unroll
      for (int ii = 0; ii < 4; ++ii) {
        int i = (q & 1) * 4 + ii;
        int lr = ii * 16 + (lane >> 4) * 4;            // row within quarter
        #pragma unroll
        for (int j = 0; j < 4; ++j) {
          int lc = wcol * 64 + j * 16 + (lane & 15);   // col within 256
          #pragma unroll
          for (int r = 0; r < 4; ++r)
            Cs[(lr + r) * 260 + lc] = acc[i][j][r];
        }
      }
    }
    __syncthreads();
    // linear readback: 64 x 256 fp32 = 4096 float4, 512 thr -> 8 each
    #pragma unroll
    for (int io = 0; io < 8; ++io) {
      int idx = io * 512 + tid;
      int r = idx >> 6, c4 = (idx & 63) * 4;
      float4 v = *(const float4*)&Cs[r * 260 + c4];
      int grow = m0 + q * 64 + r;
      int gcol = n0 + c4;
      float4 bv = bias ? *(const float4*)&bias[gcol] : make_float4(0, 0, 0, 0);
      v.x = v.x * scale + bv.x; v.y = v.y * scale + bv.y;
      v.z = v.z * scale + bv.z; v.w = v.w * scale + bv.w;
      store4(C + (size_t)grow * ldc + gcol, v);
    }
  }
}

// ---------------------------------------------------------------------------
// Host-side launcher.  Workspace: 168 MiB (unchanged layout).
//   [W bf16 8MiB][SC 64MiB fp16 logits, first 32MiB doubles as bf16 IN copy]
//   [Qb 32][Kb 32 (becomes VT after scores)][Xb 32 (V, then attention X)]
// ---------------------------------------------------------------------------
extern "C" void kernel_launch(void* const* d_in, const int* in_sizes, int n_in,
                              void* d_out, int out_size, void* d_ws, size_t ws_size,
                              hipStream_t stream) {
  const float* query = (const float*)d_in[0];
  const float* key_  = (const float*)d_in[1];
  const float* value = (const float*)d_in[2];
  const float* Wq = (const float*)d_in[3];
  const float* bq = (const float*)d_in[4];
  const float* Wk = (const float*)d_in[5];
  const float* bk = (const float*)d_in[6];
  const float* Wv = (const float*)d_in[7];
  const float* bv = (const float*)d_in[8];
  const float* Wo = (const float*)d_in[9];
  const float* bo = (const float*)d_in[10];
  float* out = (float*)d_out;

  const int Bb = 8, S = 2048, D = 1024;
  const int MS = Bb * S;                    // 16384
  const size_t ND = (size_t)MS * D;         // 16.7M elements (32 MiB bf16)
  const size_t WD = (size_t)D * D;          // 1M elements (2 MiB bf16)

  char* ws = (char*)d_ws;
  bf16_t* Wqb = (bf16_t*)ws;                //  8 MiB of weights
  bf16_t* Wkb = Wqb + WD;
  bf16_t* Wvb = Wkb + WD;
  bf16_t* Wob = Wvb + WD;
  f16_t*  SC  = (f16_t*)(Wob + WD);         // 64 MiB: fp16 logits [8][S][S]
  bf16_t* IN  = (bf16_t*)SC;                //   overlay: bf16 input copies
  bf16_t* Qb  = (bf16_t*)((char*)SC + (size_t)Bb * S * S * 2);  // 32 MiB
  bf16_t* Kb  = Qb + ND;                    // 32 MiB; VT overlays after scores
  bf16_t* VT  = Kb;
  bf16_t* Xb  = Kb + ND;                    // 32 MiB: V bf16, then X
  // total: 168 MiB

  const int n4i = (int)(ND / 4), n4w = (int)(WD / 4);
  dim3 blk(512);

  // weights
  cvt_f32_bf16<<<dim3(n4w / 256), 256, 0, stream>>>(Wq, Wqb, n4w);
  cvt_f32_bf16<<<dim3(n4w / 256), 256, 0, stream>>>(Wk, Wkb, n4w);
  cvt_f32_bf16<<<dim3(n4w / 256), 256, 0, stream>>>(Wv, Wvb, n4w);
  cvt_f32_bf16<<<dim3(n4w / 256), 256, 0, stream>>>(Wo, Wob, n4w);

  // projections, one input at a time through IN (M=16384, N=K=1024)
  dim3 pgrid(MS / BM, D / BN, 1);           // 256 blocks = 1/CU
  cvt_f32_bf16<<<dim3(n4i / 256), 256, 0, stream>>>(query, IN, n4i);
  gemm256<bf16_t><<<pgrid, blk, 0, stream>>>(
      IN, D, 0, Wqb, D, 0, Qb, D, 0, bq, 1.f, D, 0);
  cvt_f32_bf16<<<dim3(n4i / 256), 256, 0, stream>>>(key_, IN, n4i);
  gemm256<bf16_t><<<pgrid, blk, 0, stream>>>(
      IN, D, 0, Wkb, D, 0, Kb, D, 0, bk, 1.f, D, 0);
  cvt_f32_bf16<<<dim3(n4i / 256), 256, 0, stream>>>(value, IN, n4i);
  gemm256<bf16_t><<<pgrid, blk, 0, stream>>>(
      IN, D, 0, Wvb, D, 0, Xb, D, 0, bv, 1.f, D, 0);  // V into Xb (temp)

  // scores = Q @ K^T / sqrt(128) -> fp16 (M=N=2048/batch, K=1024).
  // batch on blockIdx.x: each XCD works one batch (Q_b+K_b L2 locality).
  gemm256<f16_t><<<dim3(Bb, S / BN, S / BM), blk, 0, stream>>>(
      Qb, D, (size_t)S * D, Kb, D, (size_t)S * D, SC, S, (size_t)S * S,
      nullptr, 0.08838834764831845f, D, 1);

  // V^T per batch: [2048,1024] -> [1024,2048] into VT (=Kb, dead after scores)
  transpose_bf16<<<dim3(D / 64, S / 64, Bb), 256, 0, stream>>>(Xb, VT, S, D);

  // softmax all rows -> bf16 P in place (row pitch 2048 elements)
  softmax_rows_f16<<<dim3(Bb * S), 256, 0, stream>>>(SC);

  // X = P @ (V^T)^T (M=2048, N=1024, K=2048 per batch), batch on x
  gemm256<bf16_t><<<dim3(Bb, D / BN, S / BM), blk, 0, stream>>>(
      (const bf16_t*)SC, S, (size_t)S * S, VT, S, (size_t)D * S,
      Xb, D, (size_t)S * D, nullptr, 1.f, S, 1);

  // out = X @ Wo^T + bo -> fp32 (M=16384, N=K=1024)
  gemm256<float><<<pgrid, blk, 0, stream>>>(
      Xb, D, 0, Wob, D, 0, out, D, 0, bo, 1.f, D, 0);
}

// Round 3
// 572.890 us; speedup vs baseline: 1.0114x; 1.0114x over previous
//
#include <hip/hip_runtime.h>
#include <hip/hip_bf16.h>
#include <math.h>

typedef __bf16 bf16_t;
typedef _Float16 f16_t;
typedef bf16_t bf16x8 __attribute__((ext_vector_type(8)));
typedef bf16_t bf16x4 __attribute__((ext_vector_type(4)));
typedef f16_t  f16x8  __attribute__((ext_vector_type(8)));
typedef f16_t  f16x4  __attribute__((ext_vector_type(4)));
typedef float  f32x4  __attribute__((ext_vector_type(4)));

// ---------------------------------------------------------------------------
// fp32 -> bf16 conversion, float4 loads, 8B stores
// ---------------------------------------------------------------------------
__global__ __launch_bounds__(256) void cvt_f32_bf16(
    const float* __restrict__ in, bf16_t* __restrict__ out, int n4) {
  int i = blockIdx.x * 256 + threadIdx.x;
  if (i >= n4) return;
  float4 v = ((const float4*)in)[i];
  bf16x4 o;
  o[0] = (bf16_t)v.x; o[1] = (bf16_t)v.y; o[2] = (bf16_t)v.z; o[3] = (bf16_t)v.w;
  ((bf16x4*)out)[i] = o;
}

// ---------------------------------------------------------------------------
// bf16 LDS-tiled transpose: in [R,C] -> out [C,R], per-batch via blockIdx.z
// ---------------------------------------------------------------------------
__global__ __launch_bounds__(256) void transpose_bf16(
    const bf16_t* __restrict__ in, bf16_t* __restrict__ out, int R, int C) {
  __shared__ bf16_t t[64][65];
  size_t boff = (size_t)blockIdx.z * R * C;
  in += boff; out += boff;
  int r0 = blockIdx.y * 64, c0 = blockIdx.x * 64;
  int x = threadIdx.x & 63, y4 = threadIdx.x >> 6;
  #pragma unroll
  for (int yy = y4; yy < 64; yy += 4)
    t[yy][x] = in[(size_t)(r0 + yy) * C + c0 + x];
  __syncthreads();
  #pragma unroll
  for (int yy = y4; yy < 64; yy += 4)
    out[(size_t)(c0 + yy) * R + r0 + x] = t[x][yy];
}

// ---------------------------------------------------------------------------
// Row softmax over fp16 logits [nrows x 2048]; overwrites each row in place
// with normalized bf16 P (same 2-byte element pitch, same row addresses).
// ---------------------------------------------------------------------------
__global__ __launch_bounds__(256) void softmax_rows_f16(f16_t* __restrict__ sc) {
  f16_t* rp = sc + (size_t)blockIdx.x * 2048;
  int tid = threadIdx.x;
  f16x8 v = ((const f16x8*)rp)[tid];
  float f[8];
  #pragma unroll
  for (int t = 0; t < 8; t++) f[t] = (float)v[t];

  float m = f[0];
  #pragma unroll
  for (int t = 1; t < 8; t++) m = fmaxf(m, f[t]);
  #pragma unroll
  for (int o = 32; o; o >>= 1) m = fmaxf(m, __shfl_xor(m, o));
  __shared__ float redm[4];
  if ((tid & 63) == 0) redm[tid >> 6] = m;
  __syncthreads();
  m = fmaxf(fmaxf(redm[0], redm[1]), fmaxf(redm[2], redm[3]));

  float s = 0.f;
  #pragma unroll
  for (int t = 0; t < 8; t++) { f[t] = __expf(f[t] - m); s += f[t]; }
  #pragma unroll
  for (int o = 32; o; o >>= 1) s += __shfl_xor(s, o);
  __shared__ float reds[4];
  if ((tid & 63) == 0) reds[tid >> 6] = s;
  __syncthreads();
  s = reds[0] + reds[1] + reds[2] + reds[3];
  float inv = 1.0f / s;

  bf16x8 o8;
  #pragma unroll
  for (int t = 0; t < 8; t++) o8[t] = (bf16_t)(f[t] * inv);
  ((bf16x8*)rp)[tid] = o8;
}

// ---------------------------------------------------------------------------
// epilogue store helpers (full-line coalesced vector stores)
// ---------------------------------------------------------------------------
__device__ __forceinline__ void store4(float* p, float4 v) { *(float4*)p = v; }
__device__ __forceinline__ void store4(bf16_t* p, float4 v) {
  bf16x4 o; o[0] = (bf16_t)v.x; o[1] = (bf16_t)v.y;
  o[2] = (bf16_t)v.z; o[3] = (bf16_t)v.w; *(bf16x4*)p = o;
}
__device__ __forceinline__ void store4(f16_t* p, float4 v) {
  f16x4 o; o[0] = (f16_t)v.x; o[1] = (f16_t)v.y;
  o[2] = (f16_t)v.z; o[3] = (f16_t)v.w; *(f16x4*)p = o;
}

// ---------------------------------------------------------------------------
// 256x256 8-phase bf16 MFMA GEMM, C = scale * (A @ B^T) + bias.
//   A [M,K] row-major (lda), B [N,K] row-major (ldb), C [M,N] (ldc).
//   512 threads = 8 waves (2 Mwave x 4 Nwave), per-wave C = 128x64.
// LDS: 10-slot ring of 16KB half-slots (160 KiB). Half h (tile h>>2; kind
// h&3: 0=A0,1=A1,2=B0,3=B1) lives in slot h%10; tile t stages t+2's halves
// in its 4 phases (full K-tile prefetch lead).
// SOFTWARE-PIPELINED ds_reads (this round's change): every MFMA cluster
// except ph3's consumes fragments issued >=1 phase earlier, so LDS read
// service overlaps MFMA issue instead of serializing inside the phase.
//   ph1: read a4-7(t)          -> used ph2/ph3
//   ph3: read b23(t) into bb   (b01 dead after ph2; same regs)
//   ph4 (after MFMAs): read a0-3(t+1), b01(t+1) into dead a0/bb regs
// No explicit lgkmcnt -- compiler emits exact counted waits (m97-verified).
// Cross-wave residency of tile t+1 for ph4's next-tile reads: vmcnt(6)
// (t<=nk-3; else vmcnt(0)) before ph3's pre-MFMA barrier drains all 8 of
// t+1's stage instrs (6 newest = this tile's A0/A1/B0 stages).
// Ring overwrite safety (re-derived for the new read times): every slot's
// last ds_read completes >=2 barriers before its overwriting stage.
// Requires M%256==0, N%256==0, nk>=3, lda/ldb 8-elem aligned.
// batch_on_x=1: batch=blockIdx.x (~XCD id) for L2 locality.
// ---------------------------------------------------------------------------
#define BM 256
#define BN 256
#define BK 64

__device__ __forceinline__ void load16_lds(const bf16_t* g, bf16_t* l) {
  __builtin_amdgcn_global_load_lds(
      (__attribute__((address_space(1))) void*)const_cast<bf16_t*>(g),
      (__attribute__((address_space(3))) void*)l, 16, 0, 0);
}

template <typename CT>
__global__ __launch_bounds__(512, 2) void gemm256(
    const bf16_t* __restrict__ A, int lda, size_t strA,
    const bf16_t* __restrict__ B, int ldb, size_t strB,
    CT* __restrict__ C, int ldc, size_t strC,
    const float* __restrict__ bias, float scale,
    int K, int batch_on_x) {
  __shared__ __align__(16) char smem[10][16384];  // 160 KiB ring
  char* smem0 = &smem[0][0];

  int bz, mt, nt;
  if (batch_on_x) { bz = blockIdx.x; nt = blockIdx.y; mt = blockIdx.z; }
  else            { mt = blockIdx.x; nt = blockIdx.y; bz = blockIdx.z; }
  A += (size_t)bz * strA;
  B += (size_t)bz * strB;
  C += (size_t)bz * strC;
  int m0 = mt * BM, n0 = nt * BN;
  int tid  = threadIdx.x;
  int lane = tid & 63, wv = tid >> 6;
  int wrow = wv >> 2;        // 0..1  (128 M-rows each)
  int wcol = wv & 3;         // 0..3  (64 N-cols each)

  f32x4 acc[8][4];
  #pragma unroll
  for (int i = 0; i < 8; i++)
    #pragma unroll
    for (int j = 0; j < 4; j++) acc[i][j] = (f32x4)0.f;

  int lrow = lane & 15;
  int lk8  = (lane >> 4) * 8;       // k element offset 0/8/16/24
  int xm   = (lrow & 8) << 2;       // st_16x32 read-side XOR (bit5)

  // swizzled ds_read of one bf16x8 fragment from a 16KB half-slot.
  auto rd = [&](const char* half, int blk, int kcol) -> bf16x8 {
    int byte = (((blk << 1) + (kcol >> 5)) << 10)
             + (lrow << 6) + (((kcol & 31) << 1) ^ xm);
    return *(const bf16x8*)(half + byte);
  };

  // stage logical half h into ring slot `slot`. LDS dest linear; global
  // source inverse-swizzled so swizzled ds_reads see (row, col) correctly.
  auto stage_half = [&](int h, int slot) {
    int th = h >> 2, hf = h & 3;
    char* dstb = smem0 + slot * 16384;
    const bf16_t* g; int rb, ld;
    if (hf < 2) { g = A; rb = m0 + hf * 128;       ld = lda; }
    else        { g = B; rb = n0 + (hf - 2) * 128; ld = ldb; }
    int k0 = th * BK;
    #pragma unroll
    for (int q = 0; q < 2; q++) {
      int l = q * 8192 + wv * 1024 + lane * 16;  // byte offset within half
      int inner = l & 1023, s = l >> 10;
      int rl   = ((s >> 1) << 4) | (inner >> 6);
      int colb = (inner & 63) ^ (((inner >> 9) & 1) << 5);
      int col  = ((s & 1) << 5) | (colb >> 1);
      load16_lds(g + (size_t)(rb + rl) * ld + k0 + col,
                 (bf16_t*)(dstb + q * 8192 + wv * 1024));
    }
  };

  int nk = K / BK;
  int nh = 4 * nk;
  int bl = (wcol & 1) * 4;          // B block base within its half

  // prologue: tiles 0 and 1 complete (halves 0..7 -> slots 0..7);
  // vmcnt(8) => tile 0 resident (cross-wave via barrier).
  #pragma unroll
  for (int h = 0; h < 8; ++h)
    if (h < nh) stage_half(h, h);
  asm volatile("s_waitcnt vmcnt(8)" ::: "memory");
  asm volatile("s_barrier" ::: "memory");

  bf16x8 a0[4][2], a1[4][2], bb[2][2];
  // pre-read tile 0's a0-3 and b01 (slots: A0=0+wrow, B=2+(wcol>>1))
  {
    const char* Ah0 = smem0 + (0 + wrow) * 16384;
    const char* Bh0 = smem0 + (2 + (wcol >> 1)) * 16384;
    #pragma unroll
    for (int i = 0; i < 4; ++i)
      #pragma unroll
      for (int s = 0; s < 2; ++s)
        a0[i][s] = rd(Ah0, i, s * 32 + lk8);
    #pragma unroll
    for (int j = 0; j < 2; ++j)
      #pragma unroll
      for (int s = 0; s < 2; ++s)
        bb[j][s] = rd(Bh0, bl + j, s * 32 + lk8);
  }

  int rs = 0;    // ring slot of current tile's half 4t (always even)
  int ss = 8;    // next stage slot

  for (int t = 0; t < nk; ++t) {
    int hb = 4 * t + 8;                       // tile t+2's first half
    int sa  = rs + wrow;                                  // <=9, no wrap
    int sb  = rs + 2 + (wcol >> 1); if (sb  >= 10) sb  -= 10;
    int san = rs + 4 + wrow;        if (san >= 10) san -= 10;
    int sbn = rs + 6 + (wcol >> 1); if (sbn >= 10) sbn -= 10;
    const char* Ah  = smem0 + sa  * 16384;    // this wave's A half, tile t
    const char* Bh  = smem0 + sb  * 16384;    // this wave's B half, tile t
    const char* Ahn = smem0 + san * 16384;    // tile t+1
    const char* Bhn = smem0 + sbn * 16384;

    // ---- phase 1: read a4-7 (for ph2/ph3); stage (t+2).A0; MFMA q00
    #pragma unroll
    for (int i = 0; i < 4; ++i)
      #pragma unroll
      for (int s = 0; s < 2; ++s)
        a1[i][s] = rd(Ah, 4 + i, s * 32 + lk8);
    if (hb + 0 < nh) { stage_half(hb + 0, ss); ss = (ss == 9) ? 0 : ss + 1; }
    asm volatile("s_barrier" ::: "memory");
    __builtin_amdgcn_s_setprio(1);
    #pragma unroll
    for (int i = 0; i < 4; ++i)
      #pragma unroll
      for (int j = 0; j < 2; ++j)
        #pragma unroll
        for (int s = 0; s < 2; ++s)
          acc[i][j] = __builtin_amdgcn_mfma_f32_16x16x32_bf16(
              a0[i][s], bb[j][s], acc[i][j], 0, 0, 0);
    __builtin_amdgcn_s_setprio(0);
    asm volatile("s_barrier" ::: "memory");

    // ---- phase 2: stage (t+2).A1; MFMA q10 (a1 read one phase ago)
    if (hb + 1 < nh) { stage_half(hb + 1, ss); ss = (ss == 9) ? 0 : ss + 1; }
    asm volatile("s_barrier" ::: "memory");
    __builtin_amdgcn_s_setprio(1);
    #pragma unroll
    for (int i = 0; i < 4; ++i)
      #pragma unroll
      for (int j = 0; j < 2; ++j)
        #pragma unroll
        for (int s = 0; s < 2; ++s)
          acc[4 + i][j] = __builtin_amdgcn_mfma_f32_16x16x32_bf16(
              a1[i][s], bb[j][s], acc[4 + i][j], 0, 0, 0);
    __builtin_amdgcn_s_setprio(0);
    asm volatile("s_barrier" ::: "memory");

    // ---- phase 3: read b23 into bb (b01 dead); stage (t+2).B0;
    //      counted vmcnt => tile t+1 fully resident after this barrier
    #pragma unroll
    for (int j = 0; j < 2; ++j)
      #pragma unroll
      for (int s = 0; s < 2; ++s)
        bb[j][s] = rd(Bh, bl + 2 + j, s * 32 + lk8);
    if (hb + 2 < nh) { stage_half(hb + 2, ss); ss = (ss == 9) ? 0 : ss + 1; }
    if (t <= nk - 3) asm volatile("s_waitcnt vmcnt(6)" ::: "memory");
    else             asm volatile("s_waitcnt vmcnt(0)" ::: "memory");
    asm volatile("s_barrier" ::: "memory");
    __builtin_amdgcn_s_setprio(1);
    #pragma unroll
    for (int i = 0; i < 4; ++i)
      #pragma unroll
      for (int j = 0; j < 2; ++j)
        #pragma unroll
        for (int s = 0; s < 2; ++s)
          acc[4 + i][2 + j] = __builtin_amdgcn_mfma_f32_16x16x32_bf16(
              a1[i][s], bb[j][s], acc[4 + i][2 + j], 0, 0, 0);
    __builtin_amdgcn_s_setprio(0);
    asm volatile("s_barrier" ::: "memory");

    // ---- phase 4: stage (t+2).B1; MFMA q01; then read t+1's a0-3 and b01
    //      into the now-dead a0/bb registers (pipelined into next tile ph1)
    if (hb + 3 < nh) { stage_half(hb + 3, ss); ss = (ss == 9) ? 0 : ss + 1; }
    asm volatile("s_barrier" ::: "memory");
    __builtin_amdgcn_s_setprio(1);
    #pragma unroll
    for (int i = 0; i < 4; ++i)
      #pragma unroll
      for (int j = 0; j < 2; ++j)
        #pragma unroll
        for (int s = 0; s < 2; ++s)
          acc[i][2 + j] = __builtin_amdgcn_mfma_f32_16x16x32_bf16(
              a0[i][s], bb[j][s], acc[i][2 + j], 0, 0, 0);
    __builtin_amdgcn_s_setprio(0);
    if (t + 1 < nk) {
      #pragma unroll
      for (int j = 0; j < 2; ++j)
        #pragma unroll
        for (int s = 0; s < 2; ++s)
          bb[j][s] = rd(Bhn, bl + j, s * 32 + lk8);
      #pragma unroll
      for (int i = 0; i < 4; ++i)
        #pragma unroll
        for (int s = 0; s < 2; ++s)
          a0[i][s] = rd(Ahn, i, s * 32 + lk8);
    }
    asm volatile("s_barrier" ::: "memory");

    rs += 4; if (rs >= 10) rs -= 10;
  }

  // ---- epilogue: repack C through LDS in 4 quarters of 64x256 fp32 ----
  // acc mapping [m89]: col = wcol*64 + j*16 + (lane&15),
  //                    row = wrow*128 + i*16 + (lane>>4)*4 + r
  float* Cs = (float*)smem0;         // 64 x 260 fp32 (~66 KB, fits ring)
  #pragma unroll
  for (int q = 0; q < 4; ++q) {
    __syncthreads();
    if (wrow == (q >> 1)) {          // wave-uniform branch
      #pragma unroll
      for (int ii = 0; ii < 4; ++ii) {
        int i = (q & 1) * 4 + ii;
        int lr = ii * 16 + (lane >> 4) * 4;            // row within quarter
        #pragma unroll
        for (int j = 0; j < 4; ++j) {
          int lc = wcol * 64 + j * 16 + (lane & 15);   // col within 256
          #pragma unroll
          for (int r = 0; r < 4; ++r)
            Cs[(lr + r) * 260 + lc] = acc[i][j][r];
        }
      }
    }
    __syncthreads();
    // linear readback: 64 x 256 fp32 = 4096 float4, 512 thr -> 8 each
    #pragma unroll
    for (int io = 0; io < 8; ++io) {
      int idx = io * 512 + tid;
      int r = idx >> 6, c4 = (idx & 63) * 4;
      float4 v = *(const float4*)&Cs[r * 260 + c4];
      int grow = m0 + q * 64 + r;
      int gcol = n0 + c4;
      float4 bv = bias ? *(const float4*)&bias[gcol] : make_float4(0, 0, 0, 0);
      v.x = v.x * scale + bv.x; v.y = v.y * scale + bv.y;
      v.z = v.z * scale + bv.z; v.w = v.w * scale + bv.w;
      store4(C + (size_t)grow * ldc + gcol, v);
    }
  }
}

// ---------------------------------------------------------------------------
// Host-side launcher.  Workspace: 168 MiB (unchanged layout).
//   [W bf16 8MiB][SC 64MiB fp16 logits, first 32MiB doubles as bf16 IN copy]
//   [Qb 32][Kb 32 (becomes VT after scores)][Xb 32 (V, then attention X)]
// ---------------------------------------------------------------------------
extern "C" void kernel_launch(void* const* d_in, const int* in_sizes, int n_in,
                              void* d_out, int out_size, void* d_ws, size_t ws_size,
                              hipStream_t stream) {
  const float* query = (const float*)d_in[0];
  const float* key_  = (const float*)d_in[1];
  const float* value = (const float*)d_in[2];
  const float* Wq = (const float*)d_in[3];
  const float* bq = (const float*)d_in[4];
  const float* Wk = (const float*)d_in[5];
  const float* bk = (const float*)d_in[6];
  const float* Wv = (const float*)d_in[7];
  const float* bv = (const float*)d_in[8];
  const float* Wo = (const float*)d_in[9];
  const float* bo = (const float*)d_in[10];
  float* out = (float*)d_out;

  const int Bb = 8, S = 2048, D = 1024;
  const int MS = Bb * S;                    // 16384
  const size_t ND = (size_t)MS * D;         // 16.7M elements (32 MiB bf16)
  const size_t WD = (size_t)D * D;          // 1M elements (2 MiB bf16)

  char* ws = (char*)d_ws;
  bf16_t* Wqb = (bf16_t*)ws;                //  8 MiB of weights
  bf16_t* Wkb = Wqb + WD;
  bf16_t* Wvb = Wkb + WD;
  bf16_t* Wob = Wvb + WD;
  f16_t*  SC  = (f16_t*)(Wob + WD);         // 64 MiB: fp16 logits [8][S][S]
  bf16_t* IN  = (bf16_t*)SC;                //   overlay: bf16 input copies
  bf16_t* Qb  = (bf16_t*)((char*)SC + (size_t)Bb * S * S * 2);  // 32 MiB
  bf16_t* Kb  = Qb + ND;                    // 32 MiB; VT overlays after scores
  bf16_t* VT  = Kb;
  bf16_t* Xb  = Kb + ND;                    // 32 MiB: V bf16, then X
  // total: 168 MiB

  const int n4i = (int)(ND / 4), n4w = (int)(WD / 4);
  dim3 blk(512);

  // weights
  cvt_f32_bf16<<<dim3(n4w / 256), 256, 0, stream>>>(Wq, Wqb, n4w);
  cvt_f32_bf16<<<dim3(n4w / 256), 256, 0, stream>>>(Wk, Wkb, n4w);
  cvt_f32_bf16<<<dim3(n4w / 256), 256, 0, stream>>>(Wv, Wvb, n4w);
  cvt_f32_bf16<<<dim3(n4w / 256), 256, 0, stream>>>(Wo, Wob, n4w);

  // projections, one input at a time through IN (M=16384, N=K=1024)
  dim3 pgrid(MS / BM, D / BN, 1);           // 256 blocks = 1/CU
  cvt_f32_bf16<<<dim3(n4i / 256), 256, 0, stream>>>(query, IN, n4i);
  gemm256<bf16_t><<<pgrid, blk, 0, stream>>>(
      IN, D, 0, Wqb, D, 0, Qb, D, 0, bq, 1.f, D, 0);
  cvt_f32_bf16<<<dim3(n4i / 256), 256, 0, stream>>>(key_, IN, n4i);
  gemm256<bf16_t><<<pgrid, blk, 0, stream>>>(
      IN, D, 0, Wkb, D, 0, Kb, D, 0, bk, 1.f, D, 0);
  cvt_f32_bf16<<<dim3(n4i / 256), 256, 0, stream>>>(value, IN, n4i);
  gemm256<bf16_t><<<pgrid, blk, 0, stream>>>(
      IN, D, 0, Wvb, D, 0, Xb, D, 0, bv, 1.f, D, 0);  // V into Xb (temp)

  // scores = Q @ K^T / sqrt(128) -> fp16 (M=N=2048/batch, K=1024).
  // batch on blockIdx.x: each XCD works one batch (Q_b+K_b L2 locality).
  gemm256<f16_t><<<dim3(Bb, S / BN, S / BM), blk, 0, stream>>>(
      Qb, D, (size_t)S * D, Kb, D, (size_t)S * D, SC, S, (size_t)S * S,
      nullptr, 0.08838834764831845f, D, 1);

  // V^T per batch: [2048,1024] -> [1024,2048] into VT (=Kb, dead after scores)
  transpose_bf16<<<dim3(D / 64, S / 64, Bb), 256, 0, stream>>>(Xb, VT, S, D);

  // softmax all rows -> bf16 P in place (row pitch 2048 elements)
  softmax_rows_f16<<<dim3(Bb * S), 256, 0, stream>>>(SC);

  // X = P @ (V^T)^T (M=2048, N=1024, K=2048 per batch), batch on x
  gemm256<bf16_t><<<dim3(Bb, D / BN, S / BM), blk, 0, stream>>>(
      (const bf16_t*)SC, S, (size_t)S * S, VT, S, (size_t)D * S,
      Xb, D, (size_t)S * D, nullptr, 1.f, S, 1);

  // out = X @ Wo^T + bo -> fp32 (M=16384, N=K=1024)
  gemm256<float><<<pgrid, blk, 0, stream>>>(
      Xb, D, 0, Wob, D, 0, out, D, 0, bo, 1.f, D, 0);
}